// Round 5
// baseline (1512.182 us; speedup 1.0000x reference)
//
#include <hip/hip_runtime.h>
#include <hip/hip_bf16.h>

typedef float  v4f __attribute__((ext_vector_type(4)));
typedef short  v8s __attribute__((ext_vector_type(8)));
typedef int    v4i __attribute__((ext_vector_type(4)));

#define DEV static __device__ __forceinline__

DEV float bf2f(unsigned short u) {
    union { unsigned int i; float f; } x; x.i = ((unsigned int)u) << 16; return x.f;
}
DEV unsigned short f2bf(float f) {
    union { float f; unsigned int i; } x; x.f = f;
    unsigned int r = x.i + 0x7fff + ((x.i >> 16) & 1);
    return (unsigned short)(r >> 16);
}
DEV float sigm(float x) { return 1.f / (1.f + __expf(-x)); }

DEV v4i pack8(const float* f) {
    v4i o;
#pragma unroll
    for (int q = 0; q < 4; ++q)
        ((unsigned int*)&o)[q] = (unsigned int)f2bf(f[2 * q]) |
                                 ((unsigned int)f2bf(f[2 * q + 1]) << 16);
    return o;
}
DEV float lo16(unsigned int x) { union { unsigned int i; float f; } u; u.i = x << 16; return u.f; }
DEV float hi16(unsigned int x) { union { unsigned int i; float f; } u; u.i = x & 0xffff0000u; return u.f; }

// ---------------------------------------------------------------------------
// bar_init: zero the 72 barrier records (160 ints each = 11520 ints)
// ---------------------------------------------------------------------------
__global__ void bar_init_k(int* __restrict__ bars) {
    bars[blockIdx.x * 256 + threadIdx.x] = 0;
}

// ---------------------------------------------------------------------------
// Hierarchical grid barrier, SYSTEM-scope fences (L2 wb+inv -> cross-XCD
// visibility of plain stores). Fresh record per barrier idx:
//   ints [grp*16] x8 group counters, [128] global counter, [144] go flag.
// 32 blocks per group (grp = bid&7). Requires all 256 blocks co-resident
// (1 block/CU via LDS size).
// ---------------------------------------------------------------------------
DEV void gridbar(int* bars, int idx) {
    __syncthreads();
    if (threadIdx.x == 0) {
        __builtin_amdgcn_fence(__ATOMIC_RELEASE, "");
        int* base = bars + idx * 160;
        const int grp = blockIdx.x & 7;
        int old = __hip_atomic_fetch_add(base + grp * 16, 1, __ATOMIC_RELAXED,
                                         __HIP_MEMORY_SCOPE_SYSTEM);
        if (old == 31) {
            int og = __hip_atomic_fetch_add(base + 128, 1, __ATOMIC_RELAXED,
                                            __HIP_MEMORY_SCOPE_SYSTEM);
            if (og == 7)
                __hip_atomic_store(base + 144, 1, __ATOMIC_RELAXED,
                                   __HIP_MEMORY_SCOPE_SYSTEM);
        }
        while (!__hip_atomic_load(base + 144, __ATOMIC_RELAXED,
                                  __HIP_MEMORY_SCOPE_SYSTEM))
            __builtin_amdgcn_s_sleep(2);
        __builtin_amdgcn_fence(__ATOMIC_ACQUIRE, "");
    }
    __syncthreads();
}

// ---------------------------------------------------------------------------
// uber_init: Wout/Weatt/enc -> bf16, emb gather -> bf16, mean -> fp32.
// 8 elems/thread, 16B loads/stores. 15,777,792 elems -> grid 7704 exact.
// ---------------------------------------------------------------------------
__global__ __launch_bounds__(256) void uber_init(
    const float* __restrict__ WoutF, const float* __restrict__ WeattF,
    const float* __restrict__ enc, const int* __restrict__ caps,
    const float* __restrict__ embed,
    unsigned short* __restrict__ Woutb, unsigned short* __restrict__ Weattb,
    unsigned short* __restrict__ encb, unsigned short* __restrict__ embb,
    float* __restrict__ meanf)
{
    const int i = (blockIdx.x * 256 + threadIdx.x) * 8;
    float f[8];
    if (i < 10240000) {                        // W_out
        *(v4f*)&f[0] = *(const v4f*)&WoutF[i]; *(v4f*)&f[4] = *(const v4f*)&WoutF[i + 4];
        *(v4i*)&Woutb[i] = pack8(f);
    } else if (i < 10895360) {                 // W_eatt
        int j = i - 10240000;
        *(v4f*)&f[0] = *(const v4f*)&WeattF[j]; *(v4f*)&f[4] = *(const v4f*)&WeattF[j + 4];
        *(v4i*)&Weattb[j] = pack8(f);
    } else if (i < 14909440) {                 // encoder_out
        int j = i - 10895360;
        *(v4f*)&f[0] = *(const v4f*)&enc[j]; *(v4f*)&f[4] = *(const v4f*)&enc[j + 4];
        *(v4i*)&encb[j] = pack8(f);
    } else if (i < 15695872) {                 // emb gather (t < 24)
        int j = i - 14909440;
        int b = j / 12288, r = j - b * 12288, t = r / 512, e = r - t * 512;
        const float* src = &embed[caps[b * 25 + t] * 512 + e];
        *(v4f*)&f[0] = *(const v4f*)src; *(v4f*)&f[4] = *(const v4f*)(src + 4);
        *(v4i*)&embb[j] = pack8(f);
    } else if (i < 15777792) {                 // mean over P=49 (fp32 out)
        int j = i - 15695872;
        int b = j / 1280, c = j - b * 1280;
#pragma unroll
        for (int q = 0; q < 8; ++q) f[q] = 0.f;
        for (int p = 0; p < 49; ++p) {
            const float* src = &enc[(b * 49 + p) * 1280 + c];
            v4f a = *(const v4f*)src, bq = *(const v4f*)(src + 4);
#pragma unroll
            for (int q = 0; q < 4; ++q) { f[q] += a[q]; f[q + 4] += bq[q]; }
        }
#pragma unroll
        for (int q = 0; q < 8; ++q) f[q] *= (1.f / 49.f);
        *(v4f*)&meanf[j] = *(v4f*)&f[0];
        *(v4f*)&meanf[j + 4] = *(v4f*)&f[4];
    }
}

// ---------------------------------------------------------------------------
// gemm_att1: att1[3136,512](bf16) = enc_b @ W_eatt^T + b. grid (8,49)
// ---------------------------------------------------------------------------
__global__ __launch_bounds__(256) void gemm_att1_k(
    const unsigned short* __restrict__ Aenc, const unsigned short* __restrict__ Bw,
    const float* __restrict__ bias, unsigned short* __restrict__ Cout)
{
    __shared__ unsigned short lA[64 * 136];
    __shared__ unsigned short lB[64 * 136];
    const int tid = threadIdx.x, lane = tid & 63, w = tid >> 6;
    const int mb = blockIdx.y * 64, nb = blockIdx.x * 64;
    const int rT = tid >> 4, cT = (tid & 15) * 8;
    v4f acc[4];
#pragma unroll
    for (int f = 0; f < 4; ++f) acc[f] = (v4f){0.f, 0.f, 0.f, 0.f};
    v4i ra[4], rb[4];
#pragma unroll
    for (int i = 0; i < 4; ++i) {
        ra[i] = *(const v4i*)&Aenc[(mb + rT + i * 16) * 1280 + cT];
        rb[i] = *(const v4i*)&Bw[(nb + rT + i * 16) * 1280 + cT];
    }
    for (int kt = 0; kt < 1280; kt += 128) {
#pragma unroll
        for (int i = 0; i < 4; ++i) {
            *(v4i*)&lA[(rT + i * 16) * 136 + cT] = ra[i];
            *(v4i*)&lB[(rT + i * 16) * 136 + cT] = rb[i];
        }
        __syncthreads();
        if (kt + 128 < 1280) {
#pragma unroll
            for (int i = 0; i < 4; ++i) {
                ra[i] = *(const v4i*)&Aenc[(mb + rT + i * 16) * 1280 + kt + 128 + cT];
                rb[i] = *(const v4i*)&Bw[(nb + rT + i * 16) * 1280 + kt + 128 + cT];
            }
        }
#pragma unroll
        for (int ks = 0; ks < 4; ++ks) {
            v8s a = *(const v8s*)&lA[(w * 16 + (lane & 15)) * 136 + ks * 32 + (lane >> 4) * 8];
#pragma unroll
            for (int f = 0; f < 4; ++f) {
                v8s b = *(const v8s*)&lB[(f * 16 + (lane & 15)) * 136 + ks * 32 + (lane >> 4) * 8];
                acc[f] = __builtin_amdgcn_mfma_f32_16x16x32_bf16(a, b, acc[f], 0, 0, 0);
            }
        }
        __syncthreads();
    }
#pragma unroll
    for (int f = 0; f < 4; ++f) {
        int n = nb + f * 16 + (lane & 15);
        float bs = bias[n];
#pragma unroll
        for (int r = 0; r < 4; ++r) {
            int m = mb + w * 16 + (lane >> 4) * 4 + r;
            Cout[m * 512 + n] = f2bf(acc[f][r] + bs);
        }
    }
}

// ---------------------------------------------------------------------------
// pers_k: 24-step recurrence, one launch. 256 blocks, 1 block/CU (133 KB LDS).
// Block g pins its 16 Wz gate-rows in LDS; blocks 0..31 pin a Wdatt slice.
// Preamble computes h0/c0 for this block's 4 h-cols; c stays in a register.
// Per step: A) att2 GEMM -> bar  B) scores/softmax/ctx -> bar  C) gates+LSTM.
// z double-buffered; emb read directly from embb in phase C.
// ---------------------------------------------------------------------------
__global__ __launch_bounds__(256, 1) void pers_k(
    const float* __restrict__ Wih, const float* __restrict__ Whh,
    const float* __restrict__ bih, const float* __restrict__ bhh,
    const float* __restrict__ Wdatt, const float* __restrict__ bdatt,
    const float* __restrict__ Wfatt, const float* __restrict__ bfatt,
    const float* __restrict__ Wh0, const float* __restrict__ bh0,
    const float* __restrict__ Wc0, const float* __restrict__ bc0,
    const float* __restrict__ meanf,
    const unsigned short* __restrict__ att1b,
    const unsigned short* __restrict__ encb,
    const unsigned short* __restrict__ embb,
    unsigned short* __restrict__ z, float* __restrict__ att2,
    unsigned short* __restrict__ Hall, int* __restrict__ bars)
{
    __shared__ unsigned short lWz[16 * 2824];   // 90368 B
    __shared__ unsigned short lWd[16 * 1032];   // 33024 B (blocks 0..31)
    __shared__ float gbuf[64 * 20];
    __shared__ float a2f[512];
    __shared__ float wf[512];
    __shared__ float es[64];
    __shared__ float alpha[64];
    __shared__ float bzs[16];

    const int tid = threadIdx.x, lane = tid & 63, w = tid >> 6;
    const int g = blockIdx.x;

    // ---- preamble: pin Wz slice (bf16) ----
    for (int r = 0; r < 16; ++r) {
        const int grow = (r & 3) * 1024 + g * 4 + (r >> 2);
        for (int c = tid * 8; c < 2816; c += 2048) {
            float f[8];
            const float* src = (c < 1792) ? &Wih[grow * 1792 + c]
                                          : &Whh[grow * 1024 + (c - 1792)];
            *(v4f*)&f[0] = *(const v4f*)src;
            *(v4f*)&f[4] = *(const v4f*)(src + 4);
            *(v4i*)&lWz[r * 2824 + c] = pack8(f);
        }
    }
    if (g < 32) {
        for (int r = 0; r < 16; ++r) {
            const int arow = g * 16 + r;
            for (int c = tid * 8; c < 1024; c += 2048) {
                float f[8];
                *(v4f*)&f[0] = *(const v4f*)&Wdatt[arow * 1024 + c];
                *(v4f*)&f[4] = *(const v4f*)&Wdatt[arow * 1024 + c + 4];
                *(v4i*)&lWd[r * 1032 + c] = pack8(f);
            }
        }
    }
    if (tid < 16) {
        const int grow = (tid & 3) * 1024 + g * 4 + (tid >> 2);
        bzs[tid] = bih[grow] + bhh[grow];
    }
    wf[tid] = Wfatt[tid]; wf[tid + 256] = Wfatt[tid + 256];
    const float bf0 = bfatt[0];

    // ---- h0 / c0 for this block's 4 h-cols (thread = (b, hc)) ----
    const int bb0 = tid >> 2, hc0 = tid & 3, hidx0 = g * 4 + hc0;
    float sh = bh0[hidx0], creg = bc0[hidx0];
    for (int k = 0; k < 1280; k += 4) {
        v4f mv = *(const v4f*)&meanf[bb0 * 1280 + k];
        v4f wh = *(const v4f*)&Wh0[hidx0 * 1280 + k];
        v4f wc = *(const v4f*)&Wc0[hidx0 * 1280 + k];
#pragma unroll
        for (int q = 0; q < 4; ++q) { sh += mv[q] * wh[q]; creg += mv[q] * wc[q]; }
    }
    z[bb0 * 2816 + 1792 + hidx0] = f2bf(sh);     // h0 -> z buffer 0

    int barid = 0;
    gridbar(bars, barid++);

    for (int t = 0; t < 24; ++t) {
        unsigned short* zcur = z + (t & 1) * 180224;
        unsigned short* znxt = z + ((t + 1) & 1) * 180224;

        // ---- phase A: att2 = h @ Wdatt^T (blocks 0..31) ----
        if (g < 32) {
            const unsigned short* zh = zcur + 1792;
            const int mrow = w * 16 + (lane & 15);
            const int ko = (lane >> 4) * 8;
            v4f acc0 = {0.f,0.f,0.f,0.f}, acc1 = {0.f,0.f,0.f,0.f};
#pragma unroll 4
            for (int kt = 0; kt < 32; kt += 2) {
                v8s a0 = *(const v8s*)&zh[mrow * 2816 + kt * 32 + ko];
                v8s b0 = *(const v8s*)&lWd[(lane & 15) * 1032 + kt * 32 + ko];
                acc0 = __builtin_amdgcn_mfma_f32_16x16x32_bf16(a0, b0, acc0, 0, 0, 0);
                v8s a1 = *(const v8s*)&zh[mrow * 2816 + kt * 32 + 32 + ko];
                v8s b1 = *(const v8s*)&lWd[(lane & 15) * 1032 + kt * 32 + 32 + ko];
                acc1 = __builtin_amdgcn_mfma_f32_16x16x32_bf16(a1, b1, acc1, 0, 0, 0);
            }
            const int n = g * 16 + (lane & 15);
#pragma unroll
            for (int r = 0; r < 4; ++r)
                att2[(w * 16 + (lane >> 4) * 4 + r) * 512 + n] = acc0[r] + acc1[r];
        }
        gridbar(bars, barid++);

        // ---- phase B: scores/softmax/ctx (b = g&63, quarter q = g>>6) ----
        {
            const int b = g & 63, q = g >> 6;
            a2f[tid]       = att2[b * 512 + tid] + bdatt[tid];
            a2f[tid + 256] = att2[b * 512 + tid + 256] + bdatt[tid + 256];
            __syncthreads();
            for (int p = w; p < 49; p += 4) {
                v4i u = *(const v4i*)&att1b[(b * 49 + p) * 512 + lane * 8];
                float s = 0.f;
#pragma unroll
                for (int qq = 0; qq < 4; ++qq) {
                    unsigned int x = ((unsigned int*)&u)[qq];
                    int a0 = lane * 8 + 2 * qq, a1 = a0 + 1;
                    s += fmaxf(lo16(x) + a2f[a0], 0.f) * wf[a0];
                    s += fmaxf(hi16(x) + a2f[a1], 0.f) * wf[a1];
                }
#pragma unroll
                for (int off = 32; off > 0; off >>= 1) s += __shfl_xor(s, off);
                if (lane == 0) es[p] = s + bf0;
            }
            __syncthreads();
            if (w == 0) {
                float v = (lane < 49) ? es[lane] : -1e30f;
                float m = v;
#pragma unroll
                for (int off = 32; off > 0; off >>= 1) m = fmaxf(m, __shfl_xor(m, off));
                float e = (lane < 49) ? __expf(v - m) : 0.f;
                float s = e;
#pragma unroll
                for (int off = 32; off > 0; off >>= 1) s += __shfl_xor(s, off);
                if (lane < 49) alpha[lane] = e / s;
            }
            __syncthreads();
            if (tid < 40) {
                const int jb = q * 320 + tid * 8;
                float acc8[8];
#pragma unroll
                for (int qq = 0; qq < 8; ++qq) acc8[qq] = 0.f;
#pragma unroll 7
                for (int p = 0; p < 49; ++p) {
                    v4i u = *(const v4i*)&encb[(b * 49 + p) * 1280 + jb];
                    float al = alpha[p];
#pragma unroll
                    for (int qq = 0; qq < 4; ++qq) {
                        unsigned int x = ((unsigned int*)&u)[qq];
                        acc8[2 * qq]     += al * lo16(x);
                        acc8[2 * qq + 1] += al * hi16(x);
                    }
                }
                *(v4i*)&zcur[b * 2816 + 512 + jb] = pack8(acc8);
            }
        }
        gridbar(bars, barid++);

        // ---- phase C: gates GEMM (A: embb + z, B: LDS) + fused LSTM ----
        {
            const int mrow = w * 16 + (lane & 15);
            const int ko = (lane >> 4) * 8;
            v4f acc0 = {0.f,0.f,0.f,0.f}, acc1 = {0.f,0.f,0.f,0.f};
#pragma unroll 4
            for (int kt = 0; kt < 16; kt += 2) {           // emb part (k<512)
                v8s a0 = *(const v8s*)&embb[(mrow * 24 + t) * 512 + kt * 32 + ko];
                v8s b0 = *(const v8s*)&lWz[(lane & 15) * 2824 + kt * 32 + ko];
                acc0 = __builtin_amdgcn_mfma_f32_16x16x32_bf16(a0, b0, acc0, 0, 0, 0);
                v8s a1 = *(const v8s*)&embb[(mrow * 24 + t) * 512 + kt * 32 + 32 + ko];
                v8s b1 = *(const v8s*)&lWz[(lane & 15) * 2824 + kt * 32 + 32 + ko];
                acc1 = __builtin_amdgcn_mfma_f32_16x16x32_bf16(a1, b1, acc1, 0, 0, 0);
            }
#pragma unroll 4
            for (int kt = 16; kt < 88; kt += 2) {          // ctx + h part
                v8s a0 = *(const v8s*)&zcur[mrow * 2816 + kt * 32 + ko];
                v8s b0 = *(const v8s*)&lWz[(lane & 15) * 2824 + kt * 32 + ko];
                acc0 = __builtin_amdgcn_mfma_f32_16x16x32_bf16(a0, b0, acc0, 0, 0, 0);
                v8s a1 = *(const v8s*)&zcur[mrow * 2816 + kt * 32 + 32 + ko];
                v8s b1 = *(const v8s*)&lWz[(lane & 15) * 2824 + kt * 32 + 32 + ko];
                acc1 = __builtin_amdgcn_mfma_f32_16x16x32_bf16(a1, b1, acc1, 0, 0, 0);
            }
#pragma unroll
            for (int r = 0; r < 4; ++r)
                gbuf[(w * 16 + (lane >> 4) * 4 + r) * 20 + (lane & 15)] =
                    acc0[r] + acc1[r];
            __syncthreads();
            const int b = tid >> 2, hc2 = tid & 3, hidx = g * 4 + hc2;
            float gi = gbuf[b * 20 + hc2 * 4 + 0] + bzs[hc2 * 4 + 0];
            float gf = gbuf[b * 20 + hc2 * 4 + 1] + bzs[hc2 * 4 + 1];
            float gg = gbuf[b * 20 + hc2 * 4 + 2] + bzs[hc2 * 4 + 2];
            float go = gbuf[b * 20 + hc2 * 4 + 3] + bzs[hc2 * 4 + 3];
            float cn = sigm(gf) * creg + sigm(gi) * tanhf(gg);
            float hn = sigm(go) * tanhf(cn);
            creg = cn;
            unsigned short hb16 = f2bf(hn);
            znxt[b * 2816 + 1792 + hidx] = hb16;
            Hall[t * 65536 + b * 1024 + hidx] = hb16;
        }
        if (t != 23) gridbar(bars, barid++);
    }
}

// ---------------------------------------------------------------------------
// preds: out = Hall[1536,1024] @ W_out[10000,1024]^T + b_out. 128x128 tiles,
// XCD-swizzled so each n-strip's 12 m-blocks share an XCD L2.
// ---------------------------------------------------------------------------
__global__ __launch_bounds__(256) void preds_k(
    const unsigned short* __restrict__ Hall, const unsigned short* __restrict__ Wout,
    const float* __restrict__ bout, float* __restrict__ out)
{
    const int bid = blockIdx.x;
    const int x = bid & 7, q = bid >> 3;
    int m, n;
    if (x < 7) { m = q / 10; n = x * 10 + q % 10; }
    else       { m = q / 9;  n = 70 + q % 9; if (m >= 12) return; }
    const int mb = m * 128, nb = n * 128;

    __shared__ unsigned short lA[128 * 72];
    __shared__ unsigned short lB[128 * 72];
    const int tid = threadIdx.x, lane = tid & 63, w = tid >> 6;
    const int rT = tid >> 3, cT = (tid & 7) * 8;
    v4f acc[2][8];
#pragma unroll
    for (int i = 0; i < 2; ++i)
#pragma unroll
        for (int f = 0; f < 8; ++f) acc[i][f] = (v4f){0.f, 0.f, 0.f, 0.f};
    v4i ra[4], rb[4];
#pragma unroll
    for (int i = 0; i < 4; ++i) {
        ra[i] = *(const v4i*)&Hall[(mb + rT + i * 32) * 1024 + cT];
        int n2 = nb + rT + i * 32; if (n2 > 9999) n2 = 9999;
        rb[i] = *(const v4i*)&Wout[n2 * 1024 + cT];
    }
    for (int kt = 0; kt < 1024; kt += 64) {
#pragma unroll
        for (int i = 0; i < 4; ++i) {
            *(v4i*)&lA[(rT + i * 32) * 72 + cT] = ra[i];
            *(v4i*)&lB[(rT + i * 32) * 72 + cT] = rb[i];
        }
        __syncthreads();
        if (kt + 64 < 1024) {
#pragma unroll
            for (int i = 0; i < 4; ++i) {
                ra[i] = *(const v4i*)&Hall[(mb + rT + i * 32) * 1024 + kt + 64 + cT];
                int n2 = nb + rT + i * 32; if (n2 > 9999) n2 = 9999;
                rb[i] = *(const v4i*)&Wout[n2 * 1024 + kt + 64 + cT];
            }
        }
#pragma unroll
        for (int ks = 0; ks < 2; ++ks) {
            int ko = ks * 32 + (lane >> 4) * 8;
            v8s a0 = *(const v8s*)&lA[(w * 32 + (lane & 15)) * 72 + ko];
            v8s a1 = *(const v8s*)&lA[(w * 32 + 16 + (lane & 15)) * 72 + ko];
#pragma unroll
            for (int f = 0; f < 8; ++f) {
                v8s b = *(const v8s*)&lB[(f * 16 + (lane & 15)) * 72 + ko];
                acc[0][f] = __builtin_amdgcn_mfma_f32_16x16x32_bf16(a0, b, acc[0][f], 0, 0, 0);
                acc[1][f] = __builtin_amdgcn_mfma_f32_16x16x32_bf16(a1, b, acc[1][f], 0, 0, 0);
            }
        }
        __syncthreads();
    }
#pragma unroll
    for (int f = 0; f < 8; ++f) {
        int nn = nb + f * 16 + (lane & 15);
        if (nn < 10000) {
            float bs = bout[nn];
#pragma unroll
            for (int i = 0; i < 2; ++i)
#pragma unroll
                for (int r = 0; r < 4; ++r) {
                    int mm = mb + w * 32 + i * 16 + (lane >> 4) * 4 + r;
                    int tt = mm >> 6, bb = mm & 63;
                    out[(bb * 24 + tt) * 10000 + nn] = acc[i][f][r] + bs;
                }
        }
    }
}

// ---------------------------------------------------------------------------
extern "C" void kernel_launch(void* const* d_in, const int* in_sizes, int n_in,
                              void* d_out, int out_size, void* d_ws, size_t ws_size,
                              hipStream_t stream)
{
    const float* enc   = (const float*)d_in[0];
    const int*   caps  = (const int*)d_in[1];
    const float* embed = (const float*)d_in[2];
    const float* Weatt = (const float*)d_in[3];
    const float* beatt = (const float*)d_in[4];
    const float* Wdatt = (const float*)d_in[5];
    const float* bdatt = (const float*)d_in[6];
    const float* Wfatt = (const float*)d_in[7];
    const float* bfatt = (const float*)d_in[8];
    const float* Wih   = (const float*)d_in[9];
    const float* bih   = (const float*)d_in[10];
    const float* Whh   = (const float*)d_in[11];
    const float* bhh   = (const float*)d_in[12];
    const float* Wh0   = (const float*)d_in[13];
    const float* bh0   = (const float*)d_in[14];
    const float* Wc0   = (const float*)d_in[15];
    const float* bc0   = (const float*)d_in[16];
    const float* WoutF = (const float*)d_in[17];
    const float* bout  = (const float*)d_in[18];
    float* out = (float*)d_out;

    char* ws = (char*)d_ws;
    size_t off = 0;
    auto carve = [&](size_t bytes) -> void* {
        void* p = ws + off; off += (bytes + 255) & ~(size_t)255; return p;
    };
    unsigned short* Woutb  = (unsigned short*)carve(10240000ull * 2);
    unsigned short* Weattb = (unsigned short*)carve(655360ull * 2);
    unsigned short* encb   = (unsigned short*)carve(4014080ull * 2);
    unsigned short* embb   = (unsigned short*)carve(786432ull * 2);
    float*          meanf  = (float*)carve(81920ull * 4);
    unsigned short* att1b  = (unsigned short*)carve(1605632ull * 2);
    unsigned short* Hallb  = (unsigned short*)carve(1572864ull * 2);
    unsigned short* zb     = (unsigned short*)carve(360448ull * 2);   // 2 buffers
    float* att2 = (float*)carve(32768ull * 4);
    int*   bars = (int*)carve(11520ull * 4);

    bar_init_k<<<45, 256, 0, stream>>>(bars);

    uber_init<<<7704, 256, 0, stream>>>(WoutF, Weatt, enc, caps, embed,
        Woutb, Weattb, encb, embb, meanf);

    gemm_att1_k<<<dim3(8, 49), 256, 0, stream>>>(encb, Weattb, beatt, att1b);

    pers_k<<<256, 256, 0, stream>>>(Wih, Whh, bih, bhh, Wdatt, bdatt, Wfatt, bfatt,
        Wh0, bh0, Wc0, bc0, meanf, att1b, encb, embb, zb, att2, Hallb, bars);

    preds_k<<<960, 256, 0, stream>>>(Hallb, Woutb, bout, out);
}